// Round 2
// baseline (939.564 us; speedup 1.0000x reference)
//
#include <hip/hip_runtime.h>
#include <hip/hip_bf16.h>
#include <stdint.h>

#define IN_CH 50
#define OUT_CH 121
#define OUT_PAD 128
#define LDS_STRIDE 136   // 128 + 8 bf16 pad -> row stride 272 B -> <=2-way LDS bank aliasing (free)

typedef __attribute__((ext_vector_type(8))) __bf16 bf16x8;
typedef __attribute__((ext_vector_type(8))) short short8;
typedef __attribute__((ext_vector_type(4))) float f32x4;

__device__ __forceinline__ unsigned short f2bf(float f) {
  union { float f; unsigned int u; } v; v.f = f;
  unsigned int u = v.u;
  unsigned int r = u + 0x7fffu + ((u >> 16) & 1u);  // round-to-nearest-even
  return (unsigned short)(r >> 16);
}
__device__ __forceinline__ float bf2f(unsigned short b) {
  union { unsigned int u; float f; } v; v.u = ((unsigned int)b) << 16;
  return v.f;
}

// ---------------------------------------------------------------------------
// Kernel A: per-node first matmul. y[n][0:121] = bf16(x[n] @ W1), cols 121..127 = 0.
// 8 nodes per 128-thread block; W1 columns read coalesced (L1/L2 resident, 24 KB).
// ---------------------------------------------------------------------------
__global__ __launch_bounds__(128) void node_mlp1(
    const float* __restrict__ x, const float* __restrict__ W1,
    unsigned short* __restrict__ y, int Nn) {
  __shared__ float xs[8 * IN_CH];
  int nb = blockIdx.x * 8;
  int tid = threadIdx.x;
  for (int i = tid; i < 8 * IN_CH; i += 128) {
    int node = nb + i / IN_CH;
    xs[i] = (node < Nn) ? x[(size_t)nb * IN_CH + i] : 0.f;
  }
  __syncthreads();
  int c = tid;  // 0..127, output channel
  float acc[8];
#pragma unroll
  for (int n = 0; n < 8; ++n) acc[n] = 0.f;
  if (c < OUT_CH) {
    for (int k = 0; k < IN_CH; ++k) {
      float w = W1[k * OUT_CH + c];  // coalesced across threads
#pragma unroll
      for (int n = 0; n < 8; ++n) acc[n] += xs[n * IN_CH + k] * w;
    }
  }
#pragma unroll
  for (int n = 0; n < 8; ++n) {
    if (nb + n < Nn) {
      unsigned short v = (c < OUT_CH) ? f2bf(acc[n]) : (unsigned short)0;
      y[(size_t)(nb + n) * OUT_PAD + c] = v;  // 256 B/row fully coalesced
    }
  }
}

// ---------------------------------------------------------------------------
// Kernel W: W2^T as bf16, zero-padded to [128][128]. w2t[n*128+k] = bf16(W2[k][n]).
// ---------------------------------------------------------------------------
__global__ __launch_bounds__(256) void prep_w2(
    const float* __restrict__ W2, unsigned short* __restrict__ w2t) {
  int idx = blockIdx.x * 256 + threadIdx.x;  // 16384 total
  int n = idx >> 7, k = idx & 127;
  float v = (n < OUT_CH && k < OUT_CH) ? W2[k * OUT_CH + n] : 0.f;
  w2t[idx] = f2bf(v);
}

// ---------------------------------------------------------------------------
// Kernel B: per-edge gather + combine + relu + second matmul via bf16 MFMA.
// 64 edges / 256-thread block (4 waves x 16 edges). Epilogue repacked through
// LDS (reusing the W2 buffer) for fully coalesced fp32 stores.
// NOTE: edge_index is delivered as int32 by the harness (int64 in reference).
// ---------------------------------------------------------------------------
__global__ __launch_bounds__(256, 3) void edge_mlp2(
    const unsigned short* __restrict__ y,   // [N][128] bf16
    const int* __restrict__ eidx,           // [2][E] int32
    const uint4* __restrict__ w2t4,         // [2048] = [128][128] bf16
    const float* __restrict__ b1,
    const float* __restrict__ b2,
    const float* __restrict__ eps,
    float* __restrict__ out,
    int E) {
  __shared__ __align__(16) unsigned short sW[128 * LDS_STRIDE];  // 34816 B
  __shared__ __align__(16) unsigned short sH[64 * LDS_STRIDE];   // 17408 B
  __shared__ float sB1[128];
  __shared__ float sB2[128];
  int tid = threadIdx.x;

  // stage W2^T into LDS (16 B chunks; row stride 272 B = 16-aligned)
  for (int c = tid; c < 2048; c += 256) {
    int n = c >> 4, k8 = (c & 15) << 3;
    *((uint4*)&sW[n * LDS_STRIDE + k8]) = w2t4[c];
  }
  if (tid < 128) {
    sB1[tid] = (tid < OUT_CH) ? b1[tid] : 0.f;
    sB2[tid] = (tid < OUT_CH) ? b2[tid] : 0.f;
  }
  __syncthreads();

  float one_eps = 1.0f + eps[0];

  // gather + combine + relu -> sH. 4 threads per edge, 32 channels each.
  {
    int el = tid >> 2;
    int part = tid & 3;
    int e = blockIdx.x * 64 + el;
    size_t r  = (size_t)(unsigned)eidx[e];
    size_t cc = (size_t)(unsigned)eidx[E + e];
    const uint4* yr = (const uint4*)(y + r * OUT_PAD + part * 32);
    const uint4* yc = (const uint4*)(y + cc * OUT_PAD + part * 32);
#pragma unroll
    for (int q = 0; q < 4; ++q) {
      uint4 a = yr[q];
      uint4 b = yc[q];
      unsigned int aw[4] = {a.x, a.y, a.z, a.w};
      unsigned int bw[4] = {b.x, b.y, b.z, b.w};
      unsigned int hw[4];
#pragma unroll
      for (int p = 0; p < 4; ++p) {
        int ch = part * 32 + q * 8 + p * 2;
        float v0 = one_eps * bf2f((unsigned short)(aw[p] & 0xffffu)) +
                   bf2f((unsigned short)(bw[p] & 0xffffu)) + sB1[ch];
        float v1 = one_eps * bf2f((unsigned short)(aw[p] >> 16)) +
                   bf2f((unsigned short)(bw[p] >> 16)) + sB1[ch + 1];
        v0 = fmaxf(v0, 0.f);
        v1 = fmaxf(v1, 0.f);
        hw[p] = (unsigned int)f2bf(v0) | ((unsigned int)f2bf(v1) << 16);
      }
      uint4 hv;
      hv.x = hw[0]; hv.y = hw[1]; hv.z = hw[2]; hv.w = hw[3];
      *((uint4*)&sH[el * LDS_STRIDE + part * 32 + q * 8]) = hv;
    }
  }
  __syncthreads();

  // MFMA: each wave computes 16 edges x 128 out-channels, K = 128 (padded).
  int lane = tid & 63;
  int wv = tid >> 6;
  int q = lane >> 4;   // quad
  int l15 = lane & 15;

  short8 afr[4];
#pragma unroll
  for (int ks = 0; ks < 4; ++ks)  // A[m=lane&15][k=quad*8+j], m offset by wave
    afr[ks] = *(const short8*)&sH[(wv * 16 + l15) * LDS_STRIDE + q * 8 + ks * 32];

  f32x4 acc[8];
#pragma unroll
  for (int nt = 0; nt < 8; ++nt) acc[nt] = (f32x4){0.f, 0.f, 0.f, 0.f};

#pragma unroll
  for (int nt = 0; nt < 8; ++nt) {
#pragma unroll
    for (int ks = 0; ks < 4; ++ks) {
      short8 bfr = *(const short8*)&sW[(nt * 16 + l15) * LDS_STRIDE + q * 8 + ks * 32];
      acc[nt] = __builtin_amdgcn_mfma_f32_16x16x32_bf16(
          __builtin_bit_cast(bf16x8, afr[ks]),
          __builtin_bit_cast(bf16x8, bfr), acc[nt], 0, 0, 0);
    }
  }

  // Epilogue: C/D layout col=lane&15 (n), row=quad*4+reg (edge). Repack via LDS.
  __syncthreads();  // all waves done reading sW
  float* out_s = (float*)sW;  // 64*121*4 = 30976 B <= 34816 B
  int erow = wv * 16 + q * 4;
#pragma unroll
  for (int nt = 0; nt < 8; ++nt) {
    int n = nt * 16 + l15;
    if (n < OUT_CH) {
      float bb = sB2[n];
#pragma unroll
      for (int rr = 0; rr < 4; ++rr)
        out_s[(erow + rr) * OUT_CH + n] = acc[nt][rr] + bb;
    }
  }
  __syncthreads();
  size_t base = (size_t)blockIdx.x * 64 * OUT_CH;
  for (int i = tid; i < 64 * OUT_CH; i += 256)
    out[base + i] = out_s[i];  // fully coalesced fp32 stores
}

extern "C" void kernel_launch(void* const* d_in, const int* in_sizes, int n_in,
                              void* d_out, int out_size, void* d_ws, size_t ws_size,
                              hipStream_t stream) {
  const float* x      = (const float*)d_in[0];
  const int* ei       = (const int*)d_in[1];   // int64 in ref -> int32 in harness
  const float* W1     = (const float*)d_in[2];
  const float* b1     = (const float*)d_in[3];
  const float* W2     = (const float*)d_in[4];
  const float* b2     = (const float*)d_in[5];
  const float* eps    = (const float*)d_in[6];
  float* out          = (float*)d_out;

  int N = in_sizes[0] / IN_CH;            // 100000
  int E = in_sizes[1] / 2;                // 1600000

  unsigned short* y   = (unsigned short*)d_ws;              // N*128 bf16 = 25.6 MB
  unsigned short* w2t = y + (size_t)N * OUT_PAD;            // 128*128 bf16 = 32 KB

  node_mlp1<<<(N + 7) / 8, 128, 0, stream>>>(x, W1, y, N);
  prep_w2<<<64, 256, 0, stream>>>(W2, w2t);
  edge_mlp2<<<E / 64, 256, 0, stream>>>(y, ei, (const uint4*)w2t,
                                        b1, b2, eps, out, E);
}